// Round 1
// baseline (727.797 us; speedup 1.0000x reference)
//
#include <hip/hip_runtime.h>
#include <hip/hip_bf16.h>
#include <cstdint>
#include <cstddef>

// Problem constants (match reference setup_inputs)
#define NS_ 100000
#define NC_ 20000
#define NL_ 5000
#define EU_ 2000000
#define ET_ 500000
#define H_  128

// ---------------------------------------------------------------------------
// pack two fp32 into bf16x2 (round-to-nearest-even)
__device__ inline unsigned pack_bf16x2(float a, float b) {
    unsigned ua = __float_as_uint(a);
    unsigned ub = __float_as_uint(b);
    ua = (ua + 0x7fffu + ((ua >> 16) & 1u)) >> 16;
    ub = (ub + 0x7fffu + ((ub >> 16) & 1u)) >> 16;
    return (ua & 0xffffu) | (ub << 16);
}

// ---------------------------------------------------------------------------
// Input projection: out[n,128] = X[n,K] @ W[K,128] + b.
// 32 rows/block, 256 threads, each thread 4 rows x 4 cols.
// OUT_BF16: store bf16x2-packed (for h_s / h_l); else fp32 (h_c).
template <int K, bool OUT_BF16>
__global__ __launch_bounds__(256) void proj_kernel(
    const float* __restrict__ X, const float* __restrict__ W,
    const float* __restrict__ b, void* __restrict__ outp, int nrows)
{
    __shared__ float xT[K * 33];  // transposed tile, stride 33 kills bank conflicts
    const int tid = threadIdx.x;
    const int cg = tid & 31;      // col group -> cols 4*cg..4*cg+3
    const int rg = tid >> 5;      // row group -> rows 4*rg..4*rg+3
    const int row0 = blockIdx.x * 32;
    const int j0 = cg * 4;

    for (int idx = tid; idx < 32 * K; idx += 256) {
        int r = idx / K;
        int k = idx - r * K;
        int row = row0 + r;
        xT[k * 33 + r] = (row < nrows) ? X[(size_t)row * K + k] : 0.f;
    }
    __syncthreads();

    float acc[4][4];
#pragma unroll
    for (int r = 0; r < 4; r++)
#pragma unroll
        for (int i = 0; i < 4; i++) acc[r][i] = 0.f;

    for (int k = 0; k < K; k++) {
        const float4 w = *(const float4*)(W + (size_t)k * H_ + j0);
#pragma unroll
        for (int r = 0; r < 4; r++) {
            float x = xT[k * 33 + rg * 4 + r];
            acc[r][0] += x * w.x;
            acc[r][1] += x * w.y;
            acc[r][2] += x * w.z;
            acc[r][3] += x * w.w;
        }
    }

    const float4 bias = *(const float4*)(b + j0);
#pragma unroll
    for (int r = 0; r < 4; r++) {
        int row = row0 + rg * 4 + r;
        if (row >= nrows) continue;
        float c0 = acc[r][0] + bias.x;
        float c1 = acc[r][1] + bias.y;
        float c2 = acc[r][2] + bias.z;
        float c3 = acc[r][3] + bias.w;
        if constexpr (OUT_BF16) {
            unsigned* out = (unsigned*)outp;
            uint2 pk;
            pk.x = pack_bf16x2(c0, c1);
            pk.y = pack_bf16x2(c2, c3);
            *(uint2*)(out + (size_t)row * (H_ / 2) + cg * 2) = pk;
        } else {
            float* out = (float*)outp;
            float4 v = make_float4(c0, c1, c2, c3);
            *(float4*)(out + (size_t)row * H_ + j0) = v;
        }
    }
}

// ---------------------------------------------------------------------------
// Degree count
__global__ void count_kernel(const int* __restrict__ dst, int n, int* __restrict__ cnt)
{
    int i = blockIdx.x * blockDim.x + threadIdx.x;
    int stride = gridDim.x * blockDim.x;
    for (; i < n; i += stride) atomicAdd(&cnt[dst[i]], 1);
}

// Exclusive scan of cnt[0..n) -> off[0..n]; single block of 1024 threads.
__global__ __launch_bounds__(1024) void scan_kernel(
    const int* __restrict__ cnt, int* __restrict__ off, int n)
{
    __shared__ int buf[1024];
    __shared__ int carry_s;
    const int tid = threadIdx.x;
    if (tid == 0) carry_s = 0;
    __syncthreads();
    for (int base = 0; base < n; base += 1024) {
        int i = base + tid;
        int v = (i < n) ? cnt[i] : 0;
        buf[tid] = v;
        __syncthreads();
        int sum = v;
        for (int d = 1; d < 1024; d <<= 1) {
            int t = (tid >= d) ? buf[tid - d] : 0;
            __syncthreads();
            sum += t;
            buf[tid] = sum;
            __syncthreads();
        }
        int carry = carry_s;
        if (i < n) off[i] = carry + sum - v;  // exclusive
        __syncthreads();
        if (tid == 1023) carry_s = carry + sum;
        __syncthreads();
    }
    if (tid == 0) off[n] = carry_s;
}

// CSR fill: bucket src ids by dst
__global__ void fill_kernel(const int* __restrict__ src, const int* __restrict__ dst,
                            int n, const int* __restrict__ off, int* __restrict__ cur,
                            int* __restrict__ out)
{
    int i = blockIdx.x * blockDim.x + threadIdx.x;
    int stride = gridDim.x * blockDim.x;
    for (; i < n; i += stride) {
        int d = dst[i];
        int p = off[d] + atomicAdd(&cur[d], 1);
        out[p] = src[i];
    }
}

// ---------------------------------------------------------------------------
// Segment-mean gather: one wave per destination node.
// hs2: bf16x2-packed features [n_src][64 words]; agg: fp32 [NC][128]
__global__ __launch_bounds__(64) void aggregate_kernel(
    const unsigned* __restrict__ hs2, const int* __restrict__ off,
    const int* __restrict__ srcs, float* __restrict__ agg)
{
    const int c = blockIdx.x;
    const int t = threadIdx.x;  // 0..63 -> features 2t, 2t+1
    const int s0 = off[c], s1 = off[c + 1];
    float a0 = 0.f, a1 = 0.f;
    __shared__ int sbuf[64];
    for (int base = s0; base < s1; base += 64) {
        int m = s1 - base;
        if (m > 64) m = 64;
        __syncthreads();
        if (t < m) sbuf[t] = srcs[base + t];
        __syncthreads();
        for (int i = 0; i < m; i++) {
            unsigned w = hs2[(size_t)sbuf[i] * 64 + t];
            a0 += __uint_as_float(w << 16);
            a1 += __uint_as_float(w & 0xffff0000u);
        }
    }
    float inv = 1.0f / fmaxf((float)(s1 - s0), 1.0f);
    float2 v;
    v.x = a0 * inv;
    v.y = a1 * inv;
    *(float2*)(agg + (size_t)c * H_ + 2 * t) = v;
}

// ---------------------------------------------------------------------------
// Combined per-layer weights: Wc[l] = [[Wsu+Wst];[Wnu];[Wnt]] (384x128), bc = bu+bt
__global__ void prep_w_kernel(const float* __restrict__ Wsu, const float* __restrict__ Wnu,
                              const float* __restrict__ Wst, const float* __restrict__ Wnt,
                              const float* __restrict__ bu, const float* __restrict__ bt,
                              float* __restrict__ Wc, float* __restrict__ bc)
{
    int i = blockIdx.x * blockDim.x + threadIdx.x;
    const int total = 3 * 384 * H_;
    if (i < total) {
        int l = i / (384 * H_);
        int rem = i - l * 384 * H_;
        int r = rem / H_;
        int col = rem - r * H_;
        float v;
        if (r < 128)
            v = Wsu[(size_t)l * H_ * H_ + r * H_ + col] + Wst[(size_t)l * H_ * H_ + r * H_ + col];
        else if (r < 256)
            v = Wnu[(size_t)l * H_ * H_ + (r - 128) * H_ + col];
        else
            v = Wnt[(size_t)l * H_ * H_ + (r - 256) * H_ + col];
        Wc[i] = v;
    }
    if (i < 3 * H_) bc[i] = bu[i] + bt[i];
}

// ---------------------------------------------------------------------------
// One SAGE layer: out = act((A0@Wc[0:128] + A1@Wc[128:256] + A2@Wc[256:384] + bc)*scale)
// 32 rows/block, 256 threads, 4x4 register blocking, K staged per 128-segment.
__global__ __launch_bounds__(256) void layer_kernel(
    const float* __restrict__ A0, const float* __restrict__ A1,
    const float* __restrict__ A2, const float* __restrict__ Wc,
    const float* __restrict__ bc, float scale, int relu,
    float* __restrict__ out, int n)
{
    __shared__ float xT[128 * 33];
    const int tid = threadIdx.x;
    const int cg = tid & 31;
    const int rg = tid >> 5;
    const int row0 = blockIdx.x * 32;
    const int j0 = cg * 4;

    float acc[4][4];
#pragma unroll
    for (int r = 0; r < 4; r++)
#pragma unroll
        for (int i = 0; i < 4; i++) acc[r][i] = 0.f;

    const float* As[3] = {A0, A1, A2};
    for (int seg = 0; seg < 3; seg++) {
        const float* A = As[seg];
        for (int idx = tid; idx < 32 * 128; idx += 256) {
            int r = idx >> 7;
            int k = idx & 127;
            int row = row0 + r;
            xT[k * 33 + r] = (row < n) ? A[(size_t)row * H_ + k] : 0.f;
        }
        __syncthreads();
        const float* Wseg = Wc + seg * H_ * H_;
        for (int k = 0; k < 128; k++) {
            const float4 w = *(const float4*)(Wseg + k * H_ + j0);
#pragma unroll
            for (int r = 0; r < 4; r++) {
                float x = xT[k * 33 + rg * 4 + r];
                acc[r][0] += x * w.x;
                acc[r][1] += x * w.y;
                acc[r][2] += x * w.z;
                acc[r][3] += x * w.w;
            }
        }
        __syncthreads();
    }

    const float4 bias = *(const float4*)(bc + j0);
#pragma unroll
    for (int r = 0; r < 4; r++) {
        int row = row0 + rg * 4 + r;
        if (row >= n) continue;
        float4 v;
        v.x = (acc[r][0] + bias.x) * scale;
        v.y = (acc[r][1] + bias.y) * scale;
        v.z = (acc[r][2] + bias.z) * scale;
        v.w = (acc[r][3] + bias.w) * scale;
        if (relu) {
            v.x = fmaxf(v.x, 0.f);
            v.y = fmaxf(v.y, 0.f);
            v.z = fmaxf(v.z, 0.f);
            v.w = fmaxf(v.w, 0.f);
        }
        *(float4*)(out + (size_t)row * H_ + j0) = v;
    }
}

// ---------------------------------------------------------------------------
extern "C" void kernel_launch(void* const* d_in, const int* in_sizes, int n_in,
                              void* d_out, int out_size, void* d_ws, size_t ws_size,
                              hipStream_t stream)
{
    (void)in_sizes; (void)n_in; (void)out_size; (void)ws_size;
    const float* feat_s = (const float*)d_in[0];
    const float* feat_c = (const float*)d_in[1];
    const float* feat_l = (const float*)d_in[2];
    const float* W_fs = (const float*)d_in[3];
    const float* b_fs = (const float*)d_in[4];
    const float* W_fc = (const float*)d_in[5];
    const float* b_fc = (const float*)d_in[6];
    const float* W_fl = (const float*)d_in[7];
    const float* b_fl = (const float*)d_in[8];
    const float* W_self_u  = (const float*)d_in[9];
    const float* W_neigh_u = (const float*)d_in[10];
    const float* b_u = (const float*)d_in[11];
    const float* W_self_t  = (const float*)d_in[12];
    const float* W_neigh_t = (const float*)d_in[13];
    const float* b_t = (const float*)d_in[14];
    const int* und_src = (const int*)d_in[15];
    const int* und_dst = (const int*)d_in[16];
    const int* tea_src = (const int*)d_in[17];
    const int* tea_dst = (const int*)d_in[18];
    float* out = (float*)d_out;

    // workspace layout (256B aligned slices), ~79 MB total
    char* ws = (char*)d_ws;
    size_t o = 0;
    auto alloc = [&](size_t bytes) -> char* {
        char* p = ws + o;
        o += (bytes + 255) & ~(size_t)255;
        return p;
    };
    unsigned* hs2 = (unsigned*)alloc((size_t)NS_ * 64 * 4);   // h_s bf16x2
    unsigned* hl2 = (unsigned*)alloc((size_t)NL_ * 64 * 4);   // h_l bf16x2
    float* hcA  = (float*)alloc((size_t)NC_ * H_ * 4);
    float* hcB  = (float*)alloc((size_t)NC_ * H_ * 4);
    float* aggU = (float*)alloc((size_t)NC_ * H_ * 4);
    float* aggT = (float*)alloc((size_t)NC_ * H_ * 4);
    float* Wc = (float*)alloc((size_t)3 * 384 * H_ * 4);
    float* bc = (float*)alloc((size_t)3 * H_ * 4);
    int* cntU = (int*)alloc((size_t)NC_ * 4);  // cnt/cur block zeroed in one memset
    int* cntT = (int*)alloc((size_t)NC_ * 4);
    int* curU = (int*)alloc((size_t)NC_ * 4);
    int* curT = (int*)alloc((size_t)NC_ * 4);
    int* offU = (int*)alloc((size_t)(NC_ + 1) * 4);
    int* offT = (int*)alloc((size_t)(NC_ + 1) * 4);
    int* srcU = (int*)alloc((size_t)EU_ * 4);
    int* srcT = (int*)alloc((size_t)ET_ * 4);

    // zero counters + cursors (contiguous region incl. padding)
    hipMemsetAsync(cntU, 0, (size_t)((char*)offU - (char*)cntU), stream);

    // combined per-layer weights
    prep_w_kernel<<<(3 * 384 * H_ + 255) / 256, 256, 0, stream>>>(
        W_self_u, W_neigh_u, W_self_t, W_neigh_t, b_u, b_t, Wc, bc);

    // input projections
    proj_kernel<64, true><<<(NS_ + 31) / 32, 256, 0, stream>>>(feat_s, W_fs, b_fs, hs2, NS_);
    proj_kernel<128, true><<<(NL_ + 31) / 32, 256, 0, stream>>>(feat_l, W_fl, b_fl, hl2, NL_);
    proj_kernel<32, false><<<(NC_ + 31) / 32, 256, 0, stream>>>(feat_c, W_fc, b_fc, hcA, NC_);

    // CSR build for both relations
    count_kernel<<<1024, 256, 0, stream>>>(und_dst, EU_, cntU);
    count_kernel<<<1024, 256, 0, stream>>>(tea_dst, ET_, cntT);
    scan_kernel<<<1, 1024, 0, stream>>>(cntU, offU, NC_);
    scan_kernel<<<1, 1024, 0, stream>>>(cntT, offT, NC_);
    fill_kernel<<<1024, 256, 0, stream>>>(und_src, und_dst, EU_, offU, curU, srcU);
    fill_kernel<<<1024, 256, 0, stream>>>(tea_src, tea_dst, ET_, offT, curT, srcT);

    // layer-invariant neighbor means
    aggregate_kernel<<<NC_, 64, 0, stream>>>(hs2, offU, srcU, aggU);
    aggregate_kernel<<<NC_, 64, 0, stream>>>(hl2, offT, srcT, aggT);

    // 3 hetero SAGE layers (scale 0.5 on layer 0 = cross-relation 'mean'; relu on 0,1)
    layer_kernel<<<(NC_ + 31) / 32, 256, 0, stream>>>(
        hcA, aggU, aggT, Wc, bc, 0.5f, 1, hcB, NC_);
    layer_kernel<<<(NC_ + 31) / 32, 256, 0, stream>>>(
        hcB, aggU, aggT, Wc + 384 * H_, bc + H_, 1.0f, 1, hcA, NC_);
    layer_kernel<<<(NC_ + 31) / 32, 256, 0, stream>>>(
        hcA, aggU, aggT, Wc + 2 * 384 * H_, bc + 2 * H_, 1.0f, 0, out, NC_);
}

// Round 2
// 563.244 us; speedup vs baseline: 1.2922x; 1.2922x over previous
//
#include <hip/hip_runtime.h>
#include <hip/hip_bf16.h>
#include <cstdint>
#include <cstddef>

// Problem constants (match reference setup_inputs)
#define NS_ 100000
#define NC_ 20000
#define NL_ 5000
#define EU_ 2000000
#define ET_ 500000
#define H_  128

typedef __attribute__((ext_vector_type(8))) short bs8;   // 8 x bf16 (4 VGPRs)
typedef __attribute__((ext_vector_type(4))) float f32x4; // MFMA accumulator

// fp32 -> bf16 round-to-nearest-even
__device__ inline short bf_rne(float f) {
    unsigned u = __float_as_uint(f);
    u = (u + 0x7fffu + ((u >> 16) & 1u)) >> 16;
    return (short)u;
}
__device__ inline unsigned pack_bf16x2(float a, float b) {
    return ((unsigned)(unsigned short)bf_rne(a)) |
           (((unsigned)(unsigned short)bf_rne(b)) << 16);
}

// ---------------------------------------------------------------------------
// Pack combined per-layer weights into MFMA B-fragment order.
// Wc[l] = [[Wsu+Wst];[Wnu];[Wnt]] (384x128). Frag order:
// Wp[((l*12+kt)*8+nt)*64*8 + lane*8 + j] = bf16(Wc[kt*32+(lane>>4)*8+j][nt*16+(lane&15)])
__global__ __launch_bounds__(256) void pack_w_layers(
    const float* __restrict__ Wsu, const float* __restrict__ Wnu,
    const float* __restrict__ Wst, const float* __restrict__ Wnt,
    const float* __restrict__ bu, const float* __restrict__ bt,
    short* __restrict__ Wp, float* __restrict__ bc)
{
    int i = blockIdx.x * blockDim.x + threadIdx.x;
    const int total = 3 * 12 * 8 * 64 * 8;
    if (i < total) {
        int j = i & 7;
        int lane = (i >> 3) & 63;
        int nt = (i >> 9) & 7;
        int ktAll = i >> 12;           // 0..35
        int layer = ktAll / 12;
        int kt = ktAll - layer * 12;
        int k = kt * 32 + (lane >> 4) * 8 + j;
        int n = nt * 16 + (lane & 15);
        const size_t WL = (size_t)layer * H_ * H_;
        float v;
        if (k < 128)      v = Wsu[WL + k * H_ + n] + Wst[WL + k * H_ + n];
        else if (k < 256) v = Wnu[WL + (k - 128) * H_ + n];
        else              v = Wnt[WL + (k - 256) * H_ + n];
        Wp[i] = bf_rne(v);
    }
    if (i < 3 * H_) bc[i] = bu[i] + bt[i];
}

// Pack a projection weight W[K x 128] into B-fragment order (KT = K/32 tiles).
__global__ void pack_w_proj(const float* __restrict__ W, int KT, short* __restrict__ Wp)
{
    int i = blockIdx.x * blockDim.x + threadIdx.x;
    int total = KT * 8 * 64 * 8;
    if (i >= total) return;
    int j = i & 7;
    int lane = (i >> 3) & 63;
    int nt = (i >> 9) & 7;
    int kt = i >> 12;
    int k = kt * 32 + (lane >> 4) * 8 + j;
    int n = nt * 16 + (lane & 15);
    Wp[i] = bf_rne(W[(size_t)k * H_ + n]);
}

// ---------------------------------------------------------------------------
// Input projection via MFMA: out_bf16[n,128] = X[n,K] @ Wp + b.
// 4 waves/block, 16 rows/wave, 8 column tiles, KT k-steps of 32.
template <int KT>
__global__ __launch_bounds__(256) void proj_mfma(
    const float* __restrict__ X, const short* __restrict__ Wp,
    const float* __restrict__ bias, short* __restrict__ out, int n)
{
    const int lane = threadIdx.x & 63;
    const int wv = threadIdx.x >> 6;
    const int row0 = blockIdx.x * 64 + wv * 16;
    const int q = lane >> 4;
    const int rA = min(row0 + (lane & 15), n - 1);
    constexpr int K = KT * 32;
    f32x4 acc[8];
#pragma unroll
    for (int i = 0; i < 8; i++) acc[i] = (f32x4){0.f, 0.f, 0.f, 0.f};
#pragma unroll
    for (int kt = 0; kt < KT; kt++) {
        const float* xp = X + (size_t)rA * K + kt * 32 + q * 8;
        float4 xa = *(const float4*)xp;
        float4 xb = *(const float4*)(xp + 4);
        bs8 af;
        af[0] = bf_rne(xa.x); af[1] = bf_rne(xa.y); af[2] = bf_rne(xa.z); af[3] = bf_rne(xa.w);
        af[4] = bf_rne(xb.x); af[5] = bf_rne(xb.y); af[6] = bf_rne(xb.z); af[7] = bf_rne(xb.w);
        const short* wp = Wp + (size_t)kt * 8 * 512;
#pragma unroll
        for (int nt = 0; nt < 8; nt++) {
            bs8 bfr = *(const bs8*)(wp + ((size_t)nt * 64 + lane) * 8);
            acc[nt] = __builtin_amdgcn_mfma_f32_16x16x32_bf16(af, bfr, acc[nt], 0, 0, 0);
        }
    }
    const int colb = lane & 15;
#pragma unroll
    for (int nt = 0; nt < 8; nt++) {
        int col = nt * 16 + colb;
        float bv = bias[col];
#pragma unroll
        for (int r = 0; r < 4; r++) {
            int row = row0 + q * 4 + r;
            if (row < n) out[(size_t)row * H_ + col] = bf_rne(acc[nt][r] + bv);
        }
    }
}

// ---------------------------------------------------------------------------
// Build 4-way interleaved linked lists: next[i] = old head of (dst, i&3).
// next[] writes are coalesced; atomics hit only the 4*NC head array.
__global__ void link_kernel(const int* __restrict__ dst, int n,
                            int* __restrict__ head, int* __restrict__ nxt)
{
    int i = blockIdx.x * blockDim.x + threadIdx.x;
    int stride = gridDim.x * blockDim.x;
    for (; i < n; i += stride) {
        int d = dst[i];
        nxt[i] = atomicExch(&head[d * 4 + (i & 3)], i);
    }
}

// ---------------------------------------------------------------------------
// Segment-mean by walking 4 chains concurrently; one wave per destination.
// hs2: bf16x2-packed [n_src][64 words]; agg2: bf16x2 [NC][64 words]
__global__ __launch_bounds__(64) void agg_ll_kernel(
    const unsigned* __restrict__ hs2, const int* __restrict__ head,
    const int* __restrict__ nxt, const int* __restrict__ src,
    unsigned* __restrict__ agg2)
{
    const int c = blockIdx.x;
    const int t = threadIdx.x;  // feature pair 2t, 2t+1
    int p0 = head[c * 4 + 0];
    int p1 = head[c * 4 + 1];
    int p2 = head[c * 4 + 2];
    int p3 = head[c * 4 + 3];
    float a0 = 0.f, a1 = 0.f;
    int cnt = 0;
    while (p0 >= 0 || p1 >= 0 || p2 >= 0 || p3 >= 0) {
        // issue all scalar loads first (broadcast, same addr across lanes)
        int s0 = (p0 >= 0) ? src[p0] : 0;
        int s1 = (p1 >= 0) ? src[p1] : 0;
        int s2 = (p2 >= 0) ? src[p2] : 0;
        int s3 = (p3 >= 0) ? src[p3] : 0;
        int n0 = (p0 >= 0) ? nxt[p0] : -1;
        int n1 = (p1 >= 0) ? nxt[p1] : -1;
        int n2 = (p2 >= 0) ? nxt[p2] : -1;
        int n3 = (p3 >= 0) ? nxt[p3] : -1;
        if (p0 >= 0) { unsigned w = hs2[(size_t)s0 * 64 + t];
            a0 += __uint_as_float(w << 16); a1 += __uint_as_float(w & 0xffff0000u); cnt++; }
        if (p1 >= 0) { unsigned w = hs2[(size_t)s1 * 64 + t];
            a0 += __uint_as_float(w << 16); a1 += __uint_as_float(w & 0xffff0000u); cnt++; }
        if (p2 >= 0) { unsigned w = hs2[(size_t)s2 * 64 + t];
            a0 += __uint_as_float(w << 16); a1 += __uint_as_float(w & 0xffff0000u); cnt++; }
        if (p3 >= 0) { unsigned w = hs2[(size_t)s3 * 64 + t];
            a0 += __uint_as_float(w << 16); a1 += __uint_as_float(w & 0xffff0000u); cnt++; }
        p0 = n0; p1 = n1; p2 = n2; p3 = n3;
    }
    float inv = 1.f / (float)(cnt > 0 ? cnt : 1);
    agg2[(size_t)c * 64 + t] = pack_bf16x2(a0 * inv, a1 * inv);
}

// ---------------------------------------------------------------------------
// One SAGE layer via MFMA over K=384 (3 bf16 segments of 128).
// out = act(scale*(A0@W0 + A1@W1 + A2@W2 + bias)); FINAL writes fp32, no relu.
template <bool FINAL>
__global__ __launch_bounds__(256) void layer_mfma(
    const unsigned* __restrict__ A0, const unsigned* __restrict__ A1,
    const unsigned* __restrict__ A2, const short* __restrict__ Wp,
    const float* __restrict__ bias, float scale,
    short* __restrict__ out_bf, float* __restrict__ out_f32, int n)
{
    const int lane = threadIdx.x & 63;
    const int wv = threadIdx.x >> 6;
    const int row0 = blockIdx.x * 64 + wv * 16;
    const int q = lane >> 4;
    const int rA = min(row0 + (lane & 15), n - 1);
    f32x4 acc[8];
#pragma unroll
    for (int i = 0; i < 8; i++) acc[i] = (f32x4){0.f, 0.f, 0.f, 0.f};
    const unsigned* As[3] = {A0, A1, A2};
#pragma unroll
    for (int kt = 0; kt < 12; kt++) {
        const unsigned* A = As[kt >> 2];
        int ktl = kt & 3;
        bs8 af = *(const bs8*)(A + (size_t)rA * 64 + ktl * 16 + q * 4);
        const short* wp = Wp + (size_t)kt * 8 * 512;
#pragma unroll
        for (int nt = 0; nt < 8; nt++) {
            bs8 bfr = *(const bs8*)(wp + ((size_t)nt * 64 + lane) * 8);
            acc[nt] = __builtin_amdgcn_mfma_f32_16x16x32_bf16(af, bfr, acc[nt], 0, 0, 0);
        }
    }
    const int colb = lane & 15;
#pragma unroll
    for (int nt = 0; nt < 8; nt++) {
        int col = nt * 16 + colb;
        float bv = bias[col];
#pragma unroll
        for (int r = 0; r < 4; r++) {
            int row = row0 + q * 4 + r;
            if (row < n) {
                float v = (acc[nt][r] + bv) * scale;
                if constexpr (!FINAL) {
                    v = fmaxf(v, 0.f);
                    out_bf[(size_t)row * H_ + col] = bf_rne(v);
                } else {
                    out_f32[(size_t)row * H_ + col] = v;
                }
            }
        }
    }
}

// ---------------------------------------------------------------------------
extern "C" void kernel_launch(void* const* d_in, const int* in_sizes, int n_in,
                              void* d_out, int out_size, void* d_ws, size_t ws_size,
                              hipStream_t stream)
{
    (void)in_sizes; (void)n_in; (void)out_size; (void)ws_size;
    const float* feat_s = (const float*)d_in[0];
    const float* feat_c = (const float*)d_in[1];
    const float* feat_l = (const float*)d_in[2];
    const float* W_fs = (const float*)d_in[3];
    const float* b_fs = (const float*)d_in[4];
    const float* W_fc = (const float*)d_in[5];
    const float* b_fc = (const float*)d_in[6];
    const float* W_fl = (const float*)d_in[7];
    const float* b_fl = (const float*)d_in[8];
    const float* W_self_u  = (const float*)d_in[9];
    const float* W_neigh_u = (const float*)d_in[10];
    const float* b_u = (const float*)d_in[11];
    const float* W_self_t  = (const float*)d_in[12];
    const float* W_neigh_t = (const float*)d_in[13];
    const float* b_t = (const float*)d_in[14];
    const int* und_src = (const int*)d_in[15];
    const int* und_dst = (const int*)d_in[16];
    const int* tea_src = (const int*)d_in[17];
    const int* tea_dst = (const int*)d_in[18];
    float* out = (float*)d_out;

    // workspace layout (256B-aligned slices), ~58 MB total
    char* ws = (char*)d_ws;
    size_t o = 0;
    auto alloc = [&](size_t bytes) -> char* {
        char* p = ws + o;
        o += (bytes + 255) & ~(size_t)255;
        return p;
    };
    short* hs2  = (short*)alloc((size_t)NS_ * H_ * 2);  // bf16 [NS][128]
    short* hl2  = (short*)alloc((size_t)NL_ * H_ * 2);
    short* hc2A = (short*)alloc((size_t)NC_ * H_ * 2);
    short* hc2B = (short*)alloc((size_t)NC_ * H_ * 2);
    unsigned* aggU2 = (unsigned*)alloc((size_t)NC_ * 64 * 4);
    unsigned* aggT2 = (unsigned*)alloc((size_t)NC_ * 64 * 4);
    short* WpL = (short*)alloc((size_t)3 * 12 * 8 * 64 * 8 * 2);  // 294912 B
    float* bc  = (float*)alloc((size_t)3 * H_ * 4);
    short* WpS = (short*)alloc((size_t)2 * 8 * 64 * 8 * 2);
    short* WpC = (short*)alloc((size_t)1 * 8 * 64 * 8 * 2);
    short* WpF = (short*)alloc((size_t)4 * 8 * 64 * 8 * 2);
    int* headU = (int*)alloc((size_t)4 * NC_ * 4);  // 320000 B (multiple of 256)
    int* headT = (int*)alloc((size_t)4 * NC_ * 4);  // contiguous with headU
    int* nxtU  = (int*)alloc((size_t)EU_ * 4);
    int* nxtT  = (int*)alloc((size_t)ET_ * 4);

    // heads = -1
    hipMemsetAsync(headU, 0xFF, (size_t)8 * NC_ * 4, stream);

    // weight packing (tiny)
    pack_w_layers<<<(3 * 12 * 8 * 64 * 8 + 255) / 256, 256, 0, stream>>>(
        W_self_u, W_neigh_u, W_self_t, W_neigh_t, b_u, b_t, WpL, bc);
    pack_w_proj<<<(2 * 8 * 64 * 8 + 255) / 256, 256, 0, stream>>>(W_fs, 2, WpS);
    pack_w_proj<<<(1 * 8 * 64 * 8 + 255) / 256, 256, 0, stream>>>(W_fc, 1, WpC);
    pack_w_proj<<<(4 * 8 * 64 * 8 + 255) / 256, 256, 0, stream>>>(W_fl, 4, WpF);

    // input projections (MFMA, bf16 out)
    proj_mfma<2><<<(NS_ + 63) / 64, 256, 0, stream>>>(feat_s, WpS, b_fs, hs2, NS_);
    proj_mfma<4><<<(NL_ + 63) / 64, 256, 0, stream>>>(feat_l, WpF, b_fl, hl2, NL_);
    proj_mfma<1><<<(NC_ + 63) / 64, 256, 0, stream>>>(feat_c, WpC, b_fc, hc2A, NC_);

    // 4-way linked-list build (no CSR sort)
    link_kernel<<<2048, 256, 0, stream>>>(und_dst, EU_, headU, nxtU);
    link_kernel<<<2048, 256, 0, stream>>>(tea_dst, ET_, headT, nxtT);

    // layer-invariant neighbor means (chain walk + gather)
    agg_ll_kernel<<<NC_, 64, 0, stream>>>((const unsigned*)hs2, headU, nxtU, und_src, aggU2);
    agg_ll_kernel<<<NC_, 64, 0, stream>>>((const unsigned*)hl2, headT, nxtT, tea_src, aggT2);

    // 3 hetero SAGE layers (scale 0.5 on layer 0; relu on 0,1; final fp32)
    layer_mfma<false><<<(NC_ + 63) / 64, 256, 0, stream>>>(
        (const unsigned*)hc2A, aggU2, aggT2, WpL, bc, 0.5f, hc2B, nullptr, NC_);
    layer_mfma<false><<<(NC_ + 63) / 64, 256, 0, stream>>>(
        (const unsigned*)hc2B, aggU2, aggT2, WpL + 49152, bc + H_, 1.0f, hc2A, nullptr, NC_);
    layer_mfma<true><<<(NC_ + 63) / 64, 256, 0, stream>>>(
        (const unsigned*)hc2A, aggU2, aggT2, WpL + 2 * 49152, bc + 2 * H_, 1.0f,
        nullptr, out, NC_);
}

// Round 3
// 500.091 us; speedup vs baseline: 1.4553x; 1.1263x over previous
//
#include <hip/hip_runtime.h>
#include <hip/hip_bf16.h>
#include <cstdint>
#include <cstddef>

// Problem constants (match reference setup_inputs)
#define NS_ 100000
#define NC_ 20000
#define NL_ 5000
#define EU_ 2000000
#define ET_ 500000
#define H_  128

typedef __attribute__((ext_vector_type(8))) short bs8;   // 8 x bf16 (4 VGPRs)
typedef __attribute__((ext_vector_type(4))) float f32x4; // MFMA accumulator

// fp32 -> bf16 round-to-nearest-even
__device__ inline short bf_rne(float f) {
    unsigned u = __float_as_uint(f);
    u = (u + 0x7fffu + ((u >> 16) & 1u)) >> 16;
    return (short)u;
}
__device__ inline unsigned pack_bf16x2(float a, float b) {
    return ((unsigned)(unsigned short)bf_rne(a)) |
           (((unsigned)(unsigned short)bf_rne(b)) << 16);
}
__device__ inline float bflo(unsigned w) { return __uint_as_float(w << 16); }
__device__ inline float bfhi(unsigned w) { return __uint_as_float(w & 0xffff0000u); }

// ---------------------------------------------------------------------------
// fp32 -> packed bf16x2 conversion (pairs)
__global__ void cvt_bf16_kernel(const float2* __restrict__ in, unsigned* __restrict__ out, int n2)
{
    int i = blockIdx.x * blockDim.x + threadIdx.x;
    int stride = gridDim.x * blockDim.x;
    for (; i < n2; i += stride) {
        float2 v = in[i];
        out[i] = pack_bf16x2(v.x, v.y);
    }
}

// ---------------------------------------------------------------------------
// Combined layer weights with projection fold:
// Wc[l] (320x128) = [[Wsu+Wst (128)]; [W_fs @ Wnu (64)]; [W_fl @ Wnt (128)]]
__global__ __launch_bounds__(256) void prep_wc_kernel(
    const float* __restrict__ Wsu, const float* __restrict__ Wnu,
    const float* __restrict__ Wst, const float* __restrict__ Wnt,
    const float* __restrict__ W_fs, const float* __restrict__ W_fl,
    float* __restrict__ Wc)
{
    int i = blockIdx.x * 256 + threadIdx.x;
    const int total = 3 * 320 * 128;
    if (i >= total) return;
    int c = i & 127;
    int r = (i >> 7) % 320;
    int l = i / (320 * 128);
    const size_t WL = (size_t)l * H_ * H_;
    float v;
    if (r < 128) {
        v = Wsu[WL + r * H_ + c] + Wst[WL + r * H_ + c];
    } else if (r < 192) {
        int a = r - 128;
        v = 0.f;
        for (int j = 0; j < 128; j++) v += W_fs[a * H_ + j] * Wnu[WL + j * H_ + c];
    } else {
        int a = r - 192;
        v = 0.f;
        for (int j = 0; j < 128; j++) v += W_fl[a * H_ + j] * Wnt[WL + j * H_ + c];
    }
    Wc[i] = v;
}

// bc[l] = bu[l]+bt[l] + b_fs @ Wnu[l] + b_fl @ Wnt[l]
__global__ void prep_bc_kernel(
    const float* __restrict__ bu, const float* __restrict__ bt,
    const float* __restrict__ b_fs, const float* __restrict__ b_fl,
    const float* __restrict__ Wnu, const float* __restrict__ Wnt,
    float* __restrict__ bc)
{
    int i = blockIdx.x * blockDim.x + threadIdx.x;
    if (i >= 3 * H_) return;
    int l = i >> 7, c = i & 127;
    const size_t WL = (size_t)l * H_ * H_;
    float v = bu[i] + bt[i];
    for (int j = 0; j < 128; j++)
        v += b_fs[j] * Wnu[WL + j * H_ + c] + b_fl[j] * Wnt[WL + j * H_ + c];
    bc[i] = v;
}

// Pack Wc (3 layers x 320 x 128) into MFMA B-fragment order, 10 kt tiles.
__global__ __launch_bounds__(256) void pack_w_layers(
    const float* __restrict__ Wc, short* __restrict__ Wp)
{
    int i = blockIdx.x * 256 + threadIdx.x;
    const int total = 3 * 10 * 8 * 64 * 8;
    if (i >= total) return;
    int j = i & 7;
    int lane = (i >> 3) & 63;
    int nt = (i >> 9) & 7;
    int ktAll = i >> 12;            // 0..29
    int l = ktAll / 10;
    int kt = ktAll - l * 10;
    int k = kt * 32 + (lane >> 4) * 8 + j;
    int n = nt * 16 + (lane & 15);
    Wp[i] = bf_rne(Wc[(size_t)l * 320 * 128 + k * 128 + n]);
}

// Pack projection weight W[K x 128] into B-fragment order (KT k-tiles of 32).
__global__ void pack_w_proj(const float* __restrict__ W, int KT, short* __restrict__ Wp)
{
    int i = blockIdx.x * blockDim.x + threadIdx.x;
    int total = KT * 8 * 64 * 8;
    if (i >= total) return;
    int j = i & 7;
    int lane = (i >> 3) & 63;
    int nt = (i >> 9) & 7;
    int kt = i >> 12;
    int k = kt * 32 + (lane >> 4) * 8 + j;
    int n = nt * 16 + (lane & 15);
    Wp[i] = bf_rne(W[(size_t)k * H_ + n]);
}

// ---------------------------------------------------------------------------
// Input projection via MFMA: out_bf16[n,128] = X[n,K] @ Wp + b (concept feats).
template <int KT>
__global__ __launch_bounds__(256) void proj_mfma(
    const float* __restrict__ X, const short* __restrict__ Wp,
    const float* __restrict__ bias, short* __restrict__ out, int n)
{
    const int lane = threadIdx.x & 63;
    const int wv = threadIdx.x >> 6;
    const int row0 = blockIdx.x * 64 + wv * 16;
    const int q = lane >> 4;
    const int rA = min(row0 + (lane & 15), n - 1);
    constexpr int K = KT * 32;
    f32x4 acc[8];
#pragma unroll
    for (int i = 0; i < 8; i++) acc[i] = (f32x4){0.f, 0.f, 0.f, 0.f};
#pragma unroll
    for (int kt = 0; kt < KT; kt++) {
        const float* xp = X + (size_t)rA * K + kt * 32 + q * 8;
        float4 xa = *(const float4*)xp;
        float4 xb = *(const float4*)(xp + 4);
        bs8 af;
        af[0] = bf_rne(xa.x); af[1] = bf_rne(xa.y); af[2] = bf_rne(xa.z); af[3] = bf_rne(xa.w);
        af[4] = bf_rne(xb.x); af[5] = bf_rne(xb.y); af[6] = bf_rne(xb.z); af[7] = bf_rne(xb.w);
        const short* wp = Wp + (size_t)kt * 8 * 512;
#pragma unroll
        for (int nt = 0; nt < 8; nt++) {
            bs8 bfr = *(const bs8*)(wp + ((size_t)nt * 64 + lane) * 8);
            acc[nt] = __builtin_amdgcn_mfma_f32_16x16x32_bf16(af, bfr, acc[nt], 0, 0, 0);
        }
    }
    const int colb = lane & 15;
#pragma unroll
    for (int nt = 0; nt < 8; nt++) {
        int col = nt * 16 + colb;
        float bv = bias[col];
#pragma unroll
        for (int r = 0; r < 4; r++) {
            int row = row0 + q * 4 + r;
            if (row < n) out[(size_t)row * H_ + col] = bf_rne(acc[nt][r] + bv);
        }
    }
}

// ---------------------------------------------------------------------------
// Build 4-way interleaved linked lists with (src, next) packed per edge.
__global__ void link2_kernel(const int* __restrict__ dst, const int* __restrict__ src,
                             int n, int* __restrict__ head, int2* __restrict__ nxt2)
{
    int i = blockIdx.x * blockDim.x + threadIdx.x;
    int stride = gridDim.x * blockDim.x;
    for (; i < n; i += stride) {
        int d = dst[i];
        int old = atomicExch(&head[d * 4 + (i & 3)], i);
        nxt2[i] = make_int2(src[i], old);
    }
}

// ---------------------------------------------------------------------------
// und segment-mean on raw 64-dim bf16 feats (32-uint rows).
// One wave handles TWO dsts (half-wave each), 4 chains per dst.
__global__ __launch_bounds__(64) void agg_und_kernel(
    const unsigned* __restrict__ fsb, const int* __restrict__ head,
    const int2* __restrict__ nxt2, unsigned* __restrict__ aggF)
{
    const int lane = threadIdx.x;
    const int half = lane >> 5;
    const int tt = lane & 31;          // uint index in 32-uint row (feats 2tt,2tt+1)
    const int c = blockIdx.x * 2 + half;
    int p0 = head[c * 4 + 0];
    int p1 = head[c * 4 + 1];
    int p2 = head[c * 4 + 2];
    int p3 = head[c * 4 + 3];
    float a0 = 0.f, a1 = 0.f;
    int cnt = 0;
    while (p0 >= 0 || p1 >= 0 || p2 >= 0 || p3 >= 0) {
        int2 e0 = (p0 >= 0) ? nxt2[p0] : make_int2(0, -1);
        int2 e1 = (p1 >= 0) ? nxt2[p1] : make_int2(0, -1);
        int2 e2 = (p2 >= 0) ? nxt2[p2] : make_int2(0, -1);
        int2 e3 = (p3 >= 0) ? nxt2[p3] : make_int2(0, -1);
        if (p0 >= 0) { unsigned w = fsb[(size_t)e0.x * 32 + tt]; a0 += bflo(w); a1 += bfhi(w); cnt++; }
        if (p1 >= 0) { unsigned w = fsb[(size_t)e1.x * 32 + tt]; a0 += bflo(w); a1 += bfhi(w); cnt++; }
        if (p2 >= 0) { unsigned w = fsb[(size_t)e2.x * 32 + tt]; a0 += bflo(w); a1 += bfhi(w); cnt++; }
        if (p3 >= 0) { unsigned w = fsb[(size_t)e3.x * 32 + tt]; a0 += bflo(w); a1 += bfhi(w); cnt++; }
        p0 = e0.y; p1 = e1.y; p2 = e2.y; p3 = e3.y;
    }
    float inv = 1.f / (float)(cnt > 0 ? cnt : 1);
    aggF[(size_t)c * 32 + tt] = pack_bf16x2(a0 * inv, a1 * inv);
}

// tea segment-mean on raw 128-dim bf16 feats (64-uint rows), one wave per dst.
__global__ __launch_bounds__(64) void agg_tea_kernel(
    const unsigned* __restrict__ flb, const int* __restrict__ head,
    const int2* __restrict__ nxt2, unsigned* __restrict__ aggF)
{
    const int c = blockIdx.x;
    const int t = threadIdx.x;         // uint index in 64-uint row
    int p0 = head[c * 4 + 0];
    int p1 = head[c * 4 + 1];
    int p2 = head[c * 4 + 2];
    int p3 = head[c * 4 + 3];
    float a0 = 0.f, a1 = 0.f;
    int cnt = 0;
    while (p0 >= 0 || p1 >= 0 || p2 >= 0 || p3 >= 0) {
        int2 e0 = (p0 >= 0) ? nxt2[p0] : make_int2(0, -1);
        int2 e1 = (p1 >= 0) ? nxt2[p1] : make_int2(0, -1);
        int2 e2 = (p2 >= 0) ? nxt2[p2] : make_int2(0, -1);
        int2 e3 = (p3 >= 0) ? nxt2[p3] : make_int2(0, -1);
        if (p0 >= 0) { unsigned w = flb[(size_t)e0.x * 64 + t]; a0 += bflo(w); a1 += bfhi(w); cnt++; }
        if (p1 >= 0) { unsigned w = flb[(size_t)e1.x * 64 + t]; a0 += bflo(w); a1 += bfhi(w); cnt++; }
        if (p2 >= 0) { unsigned w = flb[(size_t)e2.x * 64 + t]; a0 += bflo(w); a1 += bfhi(w); cnt++; }
        if (p3 >= 0) { unsigned w = flb[(size_t)e3.x * 64 + t]; a0 += bflo(w); a1 += bfhi(w); cnt++; }
        p0 = e0.y; p1 = e1.y; p2 = e2.y; p3 = e3.y;
    }
    float inv = 1.f / (float)(cnt > 0 ? cnt : 1);
    aggF[(size_t)c * 64 + t] = pack_bf16x2(a0 * inv, a1 * inv);
}

// ---------------------------------------------------------------------------
// One SAGE layer via MFMA, K=320: [hc(128) | aggFu(64-dim feats) | aggFt(128-dim feats)]
// out = act(scale*(A @ Wc' + bc)); FINAL writes fp32, no relu.
template <bool FINAL>
__global__ __launch_bounds__(256) void layer_mfma(
    const unsigned* __restrict__ A0, const unsigned* __restrict__ A1,
    const unsigned* __restrict__ A2, const short* __restrict__ Wp,
    const float* __restrict__ bias, float scale,
    short* __restrict__ out_bf, float* __restrict__ out_f32, int n)
{
    const int lane = threadIdx.x & 63;
    const int wv = threadIdx.x >> 6;
    const int row0 = blockIdx.x * 64 + wv * 16;
    const int q = lane >> 4;
    const int rA = min(row0 + (lane & 15), n - 1);
    f32x4 acc[8];
#pragma unroll
    for (int i = 0; i < 8; i++) acc[i] = (f32x4){0.f, 0.f, 0.f, 0.f};
#pragma unroll
    for (int kt = 0; kt < 10; kt++) {
        const unsigned* A;
        int rowU, off;
        if (kt < 4)      { A = A0; rowU = 64; off = kt * 16; }
        else if (kt < 6) { A = A1; rowU = 32; off = (kt - 4) * 16; }
        else             { A = A2; rowU = 64; off = (kt - 6) * 16; }
        bs8 af = *(const bs8*)(A + (size_t)rA * rowU + off + q * 4);
        const short* wp = Wp + (size_t)kt * 8 * 512;
#pragma unroll
        for (int nt = 0; nt < 8; nt++) {
            bs8 bfr = *(const bs8*)(wp + ((size_t)nt * 64 + lane) * 8);
            acc[nt] = __builtin_amdgcn_mfma_f32_16x16x32_bf16(af, bfr, acc[nt], 0, 0, 0);
        }
    }
    const int colb = lane & 15;
#pragma unroll
    for (int nt = 0; nt < 8; nt++) {
        int col = nt * 16 + colb;
        float bv = bias[col];
#pragma unroll
        for (int r = 0; r < 4; r++) {
            int row = row0 + q * 4 + r;
            if (row < n) {
                float v = (acc[nt][r] + bv) * scale;
                if constexpr (!FINAL) {
                    v = fmaxf(v, 0.f);
                    out_bf[(size_t)row * H_ + col] = bf_rne(v);
                } else {
                    out_f32[(size_t)row * H_ + col] = v;
                }
            }
        }
    }
}

// ---------------------------------------------------------------------------
extern "C" void kernel_launch(void* const* d_in, const int* in_sizes, int n_in,
                              void* d_out, int out_size, void* d_ws, size_t ws_size,
                              hipStream_t stream)
{
    (void)in_sizes; (void)n_in; (void)out_size; (void)ws_size;
    const float* feat_s = (const float*)d_in[0];
    const float* feat_c = (const float*)d_in[1];
    const float* feat_l = (const float*)d_in[2];
    const float* W_fs = (const float*)d_in[3];
    const float* b_fs = (const float*)d_in[4];
    const float* W_fc = (const float*)d_in[5];
    const float* b_fc = (const float*)d_in[6];
    const float* W_fl = (const float*)d_in[7];
    const float* b_fl = (const float*)d_in[8];
    const float* W_self_u  = (const float*)d_in[9];
    const float* W_neigh_u = (const float*)d_in[10];
    const float* b_u = (const float*)d_in[11];
    const float* W_self_t  = (const float*)d_in[12];
    const float* W_neigh_t = (const float*)d_in[13];
    const float* b_t = (const float*)d_in[14];
    const int* und_src = (const int*)d_in[15];
    const int* und_dst = (const int*)d_in[16];
    const int* tea_src = (const int*)d_in[17];
    const int* tea_dst = (const int*)d_in[18];
    float* out = (float*)d_out;

    // workspace layout (256B-aligned slices), ~54 MB total
    char* ws = (char*)d_ws;
    size_t o = 0;
    auto alloc = [&](size_t bytes) -> char* {
        char* p = ws + o;
        o += (bytes + 255) & ~(size_t)255;
        return p;
    };
    unsigned* fsb  = (unsigned*)alloc((size_t)NS_ * 32 * 4);   // feat_s bf16 [NS][64]
    unsigned* flb  = (unsigned*)alloc((size_t)NL_ * 64 * 4);   // feat_l bf16 [NL][128]
    short* hc2A = (short*)alloc((size_t)NC_ * H_ * 2);
    short* hc2B = (short*)alloc((size_t)NC_ * H_ * 2);
    unsigned* aggFu = (unsigned*)alloc((size_t)NC_ * 32 * 4);  // mean feat_s bf16 [NC][64]
    unsigned* aggFt = (unsigned*)alloc((size_t)NC_ * 64 * 4);  // mean feat_l bf16 [NC][128]
    float* Wc  = (float*)alloc((size_t)3 * 320 * 128 * 4);
    short* WpL = (short*)alloc((size_t)3 * 10 * 8 * 64 * 8 * 2);
    float* bc  = (float*)alloc((size_t)3 * H_ * 4);
    short* WpC = (short*)alloc((size_t)1 * 8 * 64 * 8 * 2);
    int* headU = (int*)alloc((size_t)4 * NC_ * 4);   // 320000 B (mult of 256)
    int* headT = (int*)alloc((size_t)4 * NC_ * 4);   // contiguous with headU
    int2* nxt2U = (int2*)alloc((size_t)EU_ * 8);
    int2* nxt2T = (int2*)alloc((size_t)ET_ * 8);

    // heads = -1
    hipMemsetAsync(headU, 0xFF, (size_t)8 * NC_ * 4, stream);

    // feature bf16 tables
    cvt_bf16_kernel<<<1024, 256, 0, stream>>>((const float2*)feat_s, fsb, NS_ * 32);
    cvt_bf16_kernel<<<256, 256, 0, stream>>>((const float2*)feat_l, flb, NL_ * 64);

    // weight prep (projection folded into layer weights)
    prep_wc_kernel<<<(3 * 320 * 128 + 255) / 256, 256, 0, stream>>>(
        W_self_u, W_neigh_u, W_self_t, W_neigh_t, W_fs, W_fl, Wc);
    prep_bc_kernel<<<2, 256, 0, stream>>>(b_u, b_t, b_fs, b_fl, W_neigh_u, W_neigh_t, bc);
    pack_w_layers<<<(3 * 10 * 8 * 64 * 8 + 255) / 256, 256, 0, stream>>>(Wc, WpL);
    pack_w_proj<<<(8 * 64 * 8 + 255) / 256, 256, 0, stream>>>(W_fc, 1, WpC);

    // concept input projection (MFMA, bf16 out)
    proj_mfma<1><<<(NC_ + 63) / 64, 256, 0, stream>>>(feat_c, WpC, b_fc, hc2A, NC_);

    // 4-way linked-list build with packed (src,next)
    link2_kernel<<<2048, 256, 0, stream>>>(und_dst, und_src, EU_, headU, nxt2U);
    link2_kernel<<<2048, 256, 0, stream>>>(tea_dst, tea_src, ET_, headT, nxt2T);

    // layer-invariant neighbor feature means (raw-feat gather)
    agg_und_kernel<<<NC_ / 2, 64, 0, stream>>>(fsb, headU, nxt2U, aggFu);
    agg_tea_kernel<<<NC_, 64, 0, stream>>>(flb, headT, nxt2T, aggFt);

    // 3 hetero SAGE layers (scale 0.5 on layer 0; relu on 0,1; final fp32)
    layer_mfma<false><<<(NC_ + 63) / 64, 256, 0, stream>>>(
        (const unsigned*)hc2A, aggFu, aggFt, WpL, bc, 0.5f, hc2B, nullptr, NC_);
    layer_mfma<false><<<(NC_ + 63) / 64, 256, 0, stream>>>(
        (const unsigned*)hc2B, aggFu, aggFt, WpL + 40960, bc + H_, 1.0f, hc2A, nullptr, NC_);
    layer_mfma<true><<<(NC_ + 63) / 64, 256, 0, stream>>>(
        (const unsigned*)hc2A, aggFu, aggFt, WpL + 2 * 40960, bc + 2 * H_, 1.0f,
        nullptr, out, NC_);
}

// Round 4
// 410.075 us; speedup vs baseline: 1.7748x; 1.2195x over previous
//
#include <hip/hip_runtime.h>
#include <hip/hip_bf16.h>
#include <cstdint>
#include <cstddef>

// Problem constants (match reference setup_inputs)
#define NS_ 100000
#define NC_ 20000
#define NL_ 5000
#define EU_ 2000000
#define ET_ 500000
#define H_  128

typedef __attribute__((ext_vector_type(8))) short bs8;   // 8 x bf16 (4 VGPRs)
typedef __attribute__((ext_vector_type(4))) float f32x4; // MFMA accumulator

// fp32 -> bf16 round-to-nearest-even
__device__ inline short bf_rne(float f) {
    unsigned u = __float_as_uint(f);
    u = (u + 0x7fffu + ((u >> 16) & 1u)) >> 16;
    return (short)u;
}
__device__ inline unsigned pack_bf16x2(float a, float b) {
    return ((unsigned)(unsigned short)bf_rne(a)) |
           (((unsigned)(unsigned short)bf_rne(b)) << 16);
}
__device__ inline float bflo(unsigned w) { return __uint_as_float(w << 16); }
__device__ inline float bfhi(unsigned w) { return __uint_as_float(w & 0xffff0000u); }

// ---------------------------------------------------------------------------
// Fused fp32 -> packed bf16x2 conversion for feat_s and feat_l
__global__ void cvt_fused_kernel(const float2* __restrict__ fs, unsigned* __restrict__ fsb,
                                 const float2* __restrict__ fl, unsigned* __restrict__ flb)
{
    const int nS = NS_ * 32;
    const int nTot = nS + NL_ * 64;
    int i = blockIdx.x * blockDim.x + threadIdx.x;
    int stride = gridDim.x * blockDim.x;
    for (; i < nTot; i += stride) {
        if (i < nS) {
            float2 v = fs[i];
            fsb[i] = pack_bf16x2(v.x, v.y);
        } else {
            float2 v = fl[i - nS];
            flb[i - nS] = pack_bf16x2(v.x, v.y);
        }
    }
}

// ---------------------------------------------------------------------------
// Combined layer weights, projection-folded, computed DIRECTLY in MFMA
// B-fragment order. Logical Wc[l] (320x128) =
//   [[Wsu+Wst (128)]; [W_fs @ Wnu (64)]; [W_fl @ Wnt (128)]]
__global__ __launch_bounds__(256) void pack_prep_layers(
    const float* __restrict__ Wsu, const float* __restrict__ Wnu,
    const float* __restrict__ Wst, const float* __restrict__ Wnt,
    const float* __restrict__ W_fs, const float* __restrict__ W_fl,
    short* __restrict__ Wp)
{
    int i = blockIdx.x * 256 + threadIdx.x;
    const int total = 3 * 10 * 8 * 64 * 8;
    if (i >= total) return;
    int j = i & 7;
    int lane = (i >> 3) & 63;
    int nt = (i >> 9) & 7;
    int ktAll = i >> 12;            // 0..29
    int l = ktAll / 10;
    int kt = ktAll - l * 10;
    int k = kt * 32 + (lane >> 4) * 8 + j;
    int n = nt * 16 + (lane & 15);
    const size_t WL = (size_t)l * H_ * H_;
    float v;
    if (k < 128) {
        v = Wsu[WL + k * H_ + n] + Wst[WL + k * H_ + n];
    } else if (k < 192) {
        int a = k - 128;
        v = 0.f;
        for (int t = 0; t < 128; t++) v += W_fs[a * H_ + t] * Wnu[WL + t * H_ + n];
    } else {
        int a = k - 192;
        v = 0.f;
        for (int t = 0; t < 128; t++) v += W_fl[a * H_ + t] * Wnt[WL + t * H_ + n];
    }
    Wp[i] = bf_rne(v);
}

// bc[l] = bu[l]+bt[l] + b_fs @ Wnu[l] + b_fl @ Wnt[l]
__global__ void prep_bc_kernel(
    const float* __restrict__ bu, const float* __restrict__ bt,
    const float* __restrict__ b_fs, const float* __restrict__ b_fl,
    const float* __restrict__ Wnu, const float* __restrict__ Wnt,
    float* __restrict__ bc)
{
    int i = blockIdx.x * blockDim.x + threadIdx.x;
    if (i >= 3 * H_) return;
    int l = i >> 7, c = i & 127;
    const size_t WL = (size_t)l * H_ * H_;
    float v = bu[i] + bt[i];
    for (int j = 0; j < 128; j++)
        v += b_fs[j] * Wnu[WL + j * H_ + c] + b_fl[j] * Wnt[WL + j * H_ + c];
    bc[i] = v;
}

// Pack projection weight W[K x 128] into B-fragment order (KT k-tiles of 32).
__global__ void pack_w_proj(const float* __restrict__ W, int KT, short* __restrict__ Wp)
{
    int i = blockIdx.x * blockDim.x + threadIdx.x;
    int total = KT * 8 * 64 * 8;
    if (i >= total) return;
    int j = i & 7;
    int lane = (i >> 3) & 63;
    int nt = (i >> 9) & 7;
    int kt = i >> 12;
    int k = kt * 32 + (lane >> 4) * 8 + j;
    int n = nt * 16 + (lane & 15);
    Wp[i] = bf_rne(W[(size_t)k * H_ + n]);
}

// ---------------------------------------------------------------------------
// Input projection via MFMA: out_bf16[n,128] = X[n,K] @ Wp + b (concept feats).
template <int KT>
__global__ __launch_bounds__(256) void proj_mfma(
    const float* __restrict__ X, const short* __restrict__ Wp,
    const float* __restrict__ bias, short* __restrict__ out, int n)
{
    const int lane = threadIdx.x & 63;
    const int wv = threadIdx.x >> 6;
    const int row0 = blockIdx.x * 64 + wv * 16;
    const int q = lane >> 4;
    const int rA = min(row0 + (lane & 15), n - 1);
    constexpr int K = KT * 32;
    f32x4 acc[8];
#pragma unroll
    for (int i = 0; i < 8; i++) acc[i] = (f32x4){0.f, 0.f, 0.f, 0.f};
#pragma unroll
    for (int kt = 0; kt < KT; kt++) {
        const float* xp = X + (size_t)rA * K + kt * 32 + q * 8;
        float4 xa = *(const float4*)xp;
        float4 xb = *(const float4*)(xp + 4);
        bs8 af;
        af[0] = bf_rne(xa.x); af[1] = bf_rne(xa.y); af[2] = bf_rne(xa.z); af[3] = bf_rne(xa.w);
        af[4] = bf_rne(xb.x); af[5] = bf_rne(xb.y); af[6] = bf_rne(xb.z); af[7] = bf_rne(xb.w);
        const short* wp = Wp + (size_t)kt * 8 * 512;
#pragma unroll
        for (int nt = 0; nt < 8; nt++) {
            bs8 bfr = *(const bs8*)(wp + ((size_t)nt * 64 + lane) * 8);
            acc[nt] = __builtin_amdgcn_mfma_f32_16x16x32_bf16(af, bfr, acc[nt], 0, 0, 0);
        }
    }
    const int colb = lane & 15;
#pragma unroll
    for (int nt = 0; nt < 8; nt++) {
        int col = nt * 16 + colb;
        float bv = bias[col];
#pragma unroll
        for (int r = 0; r < 4; r++) {
            int row = row0 + q * 4 + r;
            if (row < n) out[(size_t)row * H_ + col] = bf_rne(acc[nt][r] + bv);
        }
    }
}

// ---------------------------------------------------------------------------
// Fused linked-list build: und (8 chains/dst) + tea (4 chains/dst).
// nxt2[i] = (src[i], previous head) — coalesced; atomics only on head arrays.
__global__ void link_fused_kernel(
    const int* __restrict__ und_dst, const int* __restrict__ und_src,
    const int* __restrict__ tea_dst, const int* __restrict__ tea_src,
    int* __restrict__ headU, int* __restrict__ headT,
    int2* __restrict__ nxt2U, int2* __restrict__ nxt2T)
{
    int i = blockIdx.x * blockDim.x + threadIdx.x;
    int stride = gridDim.x * blockDim.x;
    const int nTot = EU_ + ET_;
    for (; i < nTot; i += stride) {
        if (i < EU_) {
            int d = und_dst[i];
            int old = atomicExch(&headU[d * 8 + (i & 7)], i);
            nxt2U[i] = make_int2(und_src[i], old);
        } else {
            int e = i - EU_;
            int d = tea_dst[e];
            int old = atomicExch(&headT[d * 4 + (e & 3)], e);
            nxt2T[e] = make_int2(tea_src[e], old);
        }
    }
}

// ---------------------------------------------------------------------------
// Software-pipelined multi-chain segment-mean walker.
// CH chains; RW uints per feature row; t = this lane's uint within the row.
// Each iteration issues CH chase loads (next nodes) and CH feature-row loads
// (current nodes) concurrently — 2*CH independent streams in flight.
template <int CH, int RW>
__device__ inline void walk_chains(
    const unsigned* __restrict__ tbl, const int* __restrict__ head,
    const int2* __restrict__ nxt2, int c, int t, unsigned* __restrict__ aggF)
{
    int2 e[CH];
#pragma unroll
    for (int j = 0; j < CH; j++) {
        int p = head[c * CH + j];
        e[j] = (p >= 0) ? nxt2[p] : make_int2(-1, -1);
    }
    float a0 = 0.f, a1 = 0.f;
    int cnt = 0;
    for (;;) {
        int m = e[0].x;
#pragma unroll
        for (int j = 1; j < CH; j++) m &= e[j].x;
        if (m < 0) break;  // all chains exhausted (sentinel -1)
        int2 f[CH];
#pragma unroll
        for (int j = 0; j < CH; j++)
            f[j] = (e[j].y >= 0) ? nxt2[e[j].y] : make_int2(-1, -1);
#pragma unroll
        for (int j = 0; j < CH; j++)
            if (e[j].x >= 0) {
                unsigned w = tbl[(size_t)e[j].x * RW + t];
                a0 += bflo(w);
                a1 += bfhi(w);
                cnt++;
            }
#pragma unroll
        for (int j = 0; j < CH; j++) e[j] = f[j];
    }
    float inv = 1.f / (float)(cnt > 0 ? cnt : 1);
    aggF[(size_t)c * RW + t] = pack_bf16x2(a0 * inv, a1 * inv);
}

#define UND_BLOCKS (NC_ / 8)  // 8 dsts per 256-thread block (2 per wave)
#define TEA_BLOCKS (NC_ / 4)  // 4 dsts per block (1 per wave)

// Fused aggregation: blocks [0, UND_BLOCKS) do und, rest do tea.
__global__ __launch_bounds__(256) void agg_fused_kernel(
    const unsigned* __restrict__ fsb, const int* __restrict__ headU,
    const int2* __restrict__ nxt2U, unsigned* __restrict__ aggFu,
    const unsigned* __restrict__ flb, const int* __restrict__ headT,
    const int2* __restrict__ nxt2T, unsigned* __restrict__ aggFt)
{
    const int wv = threadIdx.x >> 6;
    const int lane = threadIdx.x & 63;
    const int b = blockIdx.x;
    if (b < UND_BLOCKS) {
        // 64-dim rows (32 uints): half-wave per dst, 8 chains
        int c = b * 8 + wv * 2 + (lane >> 5);
        walk_chains<8, 32>(fsb, headU, nxt2U, c, lane & 31, aggFu);
    } else {
        // 128-dim rows (64 uints): full wave per dst, 4 chains
        int c = (b - UND_BLOCKS) * 4 + wv;
        walk_chains<4, 64>(flb, headT, nxt2T, c, lane, aggFt);
    }
}

// ---------------------------------------------------------------------------
// One SAGE layer via MFMA, K=320: [hc(128) | aggFu(64) | aggFt(128)]
// out = act(scale*(A @ Wc' + bc)); FINAL writes fp32, no relu.
template <bool FINAL>
__global__ __launch_bounds__(256) void layer_mfma(
    const unsigned* __restrict__ A0, const unsigned* __restrict__ A1,
    const unsigned* __restrict__ A2, const short* __restrict__ Wp,
    const float* __restrict__ bias, float scale,
    short* __restrict__ out_bf, float* __restrict__ out_f32, int n)
{
    const int lane = threadIdx.x & 63;
    const int wv = threadIdx.x >> 6;
    const int row0 = blockIdx.x * 64 + wv * 16;
    const int q = lane >> 4;
    const int rA = min(row0 + (lane & 15), n - 1);
    f32x4 acc[8];
#pragma unroll
    for (int i = 0; i < 8; i++) acc[i] = (f32x4){0.f, 0.f, 0.f, 0.f};
#pragma unroll
    for (int kt = 0; kt < 10; kt++) {
        const unsigned* A;
        int rowU, off;
        if (kt < 4)      { A = A0; rowU = 64; off = kt * 16; }
        else if (kt < 6) { A = A1; rowU = 32; off = (kt - 4) * 16; }
        else             { A = A2; rowU = 64; off = (kt - 6) * 16; }
        bs8 af = *(const bs8*)(A + (size_t)rA * rowU + off + q * 4);
        const short* wp = Wp + (size_t)kt * 8 * 512;
#pragma unroll
        for (int nt = 0; nt < 8; nt++) {
            bs8 bfr = *(const bs8*)(wp + ((size_t)nt * 64 + lane) * 8);
            acc[nt] = __builtin_amdgcn_mfma_f32_16x16x32_bf16(af, bfr, acc[nt], 0, 0, 0);
        }
    }
    const int colb = lane & 15;
#pragma unroll
    for (int nt = 0; nt < 8; nt++) {
        int col = nt * 16 + colb;
        float bv = bias[col];
#pragma unroll
        for (int r = 0; r < 4; r++) {
            int row = row0 + q * 4 + r;
            if (row < n) {
                float v = (acc[nt][r] + bv) * scale;
                if constexpr (!FINAL) {
                    v = fmaxf(v, 0.f);
                    out_bf[(size_t)row * H_ + col] = bf_rne(v);
                } else {
                    out_f32[(size_t)row * H_ + col] = v;
                }
            }
        }
    }
}

// ---------------------------------------------------------------------------
extern "C" void kernel_launch(void* const* d_in, const int* in_sizes, int n_in,
                              void* d_out, int out_size, void* d_ws, size_t ws_size,
                              hipStream_t stream)
{
    (void)in_sizes; (void)n_in; (void)out_size; (void)ws_size;
    const float* feat_s = (const float*)d_in[0];
    const float* feat_c = (const float*)d_in[1];
    const float* feat_l = (const float*)d_in[2];
    const float* W_fs = (const float*)d_in[3];
    const float* b_fs = (const float*)d_in[4];
    const float* W_fc = (const float*)d_in[5];
    const float* b_fc = (const float*)d_in[6];
    const float* W_fl = (const float*)d_in[7];
    const float* b_fl = (const float*)d_in[8];
    const float* W_self_u  = (const float*)d_in[9];
    const float* W_neigh_u = (const float*)d_in[10];
    const float* b_u = (const float*)d_in[11];
    const float* W_self_t  = (const float*)d_in[12];
    const float* W_neigh_t = (const float*)d_in[13];
    const float* b_t = (const float*)d_in[14];
    const int* und_src = (const int*)d_in[15];
    const int* und_dst = (const int*)d_in[16];
    const int* tea_src = (const int*)d_in[17];
    const int* tea_dst = (const int*)d_in[18];
    float* out = (float*)d_out;

    // workspace layout (256B-aligned slices)
    char* ws = (char*)d_ws;
    size_t o = 0;
    auto alloc = [&](size_t bytes) -> char* {
        char* p = ws + o;
        o += (bytes + 255) & ~(size_t)255;
        return p;
    };
    unsigned* fsb  = (unsigned*)alloc((size_t)NS_ * 32 * 4);   // feat_s bf16 [NS][64]
    unsigned* flb  = (unsigned*)alloc((size_t)NL_ * 64 * 4);   // feat_l bf16 [NL][128]
    short* hc2A = (short*)alloc((size_t)NC_ * H_ * 2);
    short* hc2B = (short*)alloc((size_t)NC_ * H_ * 2);
    unsigned* aggFu = (unsigned*)alloc((size_t)NC_ * 32 * 4);  // mean feat_s bf16 [NC][64]
    unsigned* aggFt = (unsigned*)alloc((size_t)NC_ * 64 * 4);  // mean feat_l bf16 [NC][128]
    short* WpL = (short*)alloc((size_t)3 * 10 * 8 * 64 * 8 * 2);
    float* bc  = (float*)alloc((size_t)3 * H_ * 4);
    short* WpC = (short*)alloc((size_t)1 * 8 * 64 * 8 * 2);
    int* headU = (int*)alloc((size_t)8 * NC_ * 4);   // 640000 B (mult of 256)
    int* headT = (int*)alloc((size_t)4 * NC_ * 4);   // contiguous with headU
    int2* nxt2U = (int2*)alloc((size_t)EU_ * 8);
    int2* nxt2T = (int2*)alloc((size_t)ET_ * 8);

    // heads = -1 (U + T contiguous)
    hipMemsetAsync(headU, 0xFF, (size_t)12 * NC_ * 4, stream);

    // linked-list build (both relations in one kernel)
    link_fused_kernel<<<2048, 256, 0, stream>>>(
        und_dst, und_src, tea_dst, tea_src, headU, headT, nxt2U, nxt2T);

    // feature bf16 tables
    cvt_fused_kernel<<<1024, 256, 0, stream>>>(
        (const float2*)feat_s, fsb, (const float2*)feat_l, flb);

    // weight prep (projection folded, packed directly)
    pack_prep_layers<<<(3 * 10 * 8 * 64 * 8 + 255) / 256, 256, 0, stream>>>(
        W_self_u, W_neigh_u, W_self_t, W_neigh_t, W_fs, W_fl, WpL);
    prep_bc_kernel<<<2, 256, 0, stream>>>(b_u, b_t, b_fs, b_fl, W_neigh_u, W_neigh_t, bc);
    pack_w_proj<<<16, 256, 0, stream>>>(W_fc, 1, WpC);

    // concept input projection (MFMA, bf16 out)
    proj_mfma<1><<<(NC_ + 63) / 64, 256, 0, stream>>>(feat_c, WpC, b_fc, hc2A, NC_);

    // layer-invariant neighbor feature means (und + tea fused)
    agg_fused_kernel<<<UND_BLOCKS + TEA_BLOCKS, 256, 0, stream>>>(
        fsb, headU, nxt2U, aggFu, flb, headT, nxt2T, aggFt);

    // 3 hetero SAGE layers (scale 0.5 on layer 0; relu on 0,1; final fp32)
    layer_mfma<false><<<(NC_ + 63) / 64, 256, 0, stream>>>(
        (const unsigned*)hc2A, aggFu, aggFt, WpL, bc, 0.5f, hc2B, nullptr, NC_);
    layer_mfma<false><<<(NC_ + 63) / 64, 256, 0, stream>>>(
        (const unsigned*)hc2B, aggFu, aggFt, WpL + 40960, bc + H_, 1.0f, hc2A, nullptr, NC_);
    layer_mfma<true><<<(NC_ + 63) / 64, 256, 0, stream>>>(
        (const unsigned*)hc2A, aggFu, aggFt, WpL + 2 * 40960, bc + 2 * H_, 1.0f,
        nullptr, out, NC_);
}

// Round 5
// 375.382 us; speedup vs baseline: 1.9388x; 1.0924x over previous
//
#include <hip/hip_runtime.h>
#include <hip/hip_bf16.h>
#include <cstdint>
#include <cstddef>

// Problem constants (match reference setup_inputs)
#define NS_ 100000
#define NC_ 20000
#define NL_ 5000
#define EU_ 2000000
#define ET_ 500000
#define H_  128

typedef __attribute__((ext_vector_type(8))) short bs8;   // 8 x bf16 (4 VGPRs)
typedef __attribute__((ext_vector_type(4))) float f32x4; // MFMA accumulator
typedef __attribute__((ext_vector_type(2))) float v2f;

// fp32 -> bf16 round-to-nearest-even
__device__ inline short bf_rne(float f) {
    unsigned u = __float_as_uint(f);
    u = (u + 0x7fffu + ((u >> 16) & 1u)) >> 16;
    return (short)u;
}
__device__ inline unsigned pack_bf16x2(float a, float b) {
    return ((unsigned)(unsigned short)bf_rne(a)) |
           (((unsigned)(unsigned short)bf_rne(b)) << 16);
}
__device__ inline float bflo(unsigned w) { return __uint_as_float(w << 16); }
__device__ inline float bfhi(unsigned w) { return __uint_as_float(w & 0xffff0000u); }

// ---------------------------------------------------------------------------
// K1: fused prep. Block ranges: [link | cvt | pack-layers | bc | proj-concept]
#define B_LINK 1024
#define B_CVT  256
#define B_PACK 480   // 480*256 == 3*10*8*64*8 exactly
#define B_BC   2
#define B_PROJ 313
#define B_TOTAL (B_LINK + B_CVT + B_PACK + B_BC + B_PROJ)

__global__ __launch_bounds__(256) void prep_fused_kernel(
    const int* __restrict__ und_dst, const int* __restrict__ und_src,
    const int* __restrict__ tea_dst, const int* __restrict__ tea_src,
    int* __restrict__ headU, int* __restrict__ headT,
    int2* __restrict__ nxt2U, int2* __restrict__ nxt2T,
    const float* __restrict__ feat_s, unsigned* __restrict__ fs8,   // fp8 [NS][16u]
    const float* __restrict__ feat_l, unsigned* __restrict__ flb,   // bf16 [NL][64u]
    const float* __restrict__ Wsu, const float* __restrict__ Wnu,
    const float* __restrict__ Wst, const float* __restrict__ Wnt,
    const float* __restrict__ W_fs, const float* __restrict__ W_fl,
    short* __restrict__ WpL,
    const float* __restrict__ bu, const float* __restrict__ bt,
    const float* __restrict__ b_fs, const float* __restrict__ b_fl,
    float* __restrict__ bc,
    const float* __restrict__ feat_c, const float* __restrict__ W_fc,
    const float* __restrict__ b_fc, short* __restrict__ hc2A)
{
    __shared__ short lw[4096];  // used only by proj region (8 KB)
    const int b = blockIdx.x;
    const int tid = threadIdx.x;

    if (b < B_LINK) {
        // ---- linked-list build: und (8 chains/dst) + tea (4 chains/dst) ----
        int i = b * 256 + tid;
        const int stride = B_LINK * 256;
        const int nTot = EU_ + ET_;
        for (; i < nTot; i += stride) {
            if (i < EU_) {
                int d = und_dst[i];
                int old = atomicExch(&headU[d * 8 + (i & 7)], i);
                nxt2U[i] = make_int2(und_src[i], old);
            } else {
                int e = i - EU_;
                int d = tea_dst[e];
                int old = atomicExch(&headT[d * 4 + (e & 3)], e);
                nxt2T[e] = make_int2(tea_src[e], old);
            }
        }
    } else if (b < B_LINK + B_CVT) {
        // ---- feature tables: feat_s -> fp8 (4/uint), feat_l -> bf16x2 ----
        int i = (b - B_LINK) * 256 + tid;
        const int stride = B_CVT * 256;
        const int nS = NS_ * 16;             // uints of fp8 table
        const int nTot = nS + NL_ * 64;
        for (; i < nTot; i += stride) {
            if (i < nS) {
                const float4 v = ((const float4*)feat_s)[i];
                unsigned r = __builtin_amdgcn_cvt_pk_fp8_f32(v.x, v.y, 0, false);
                r = __builtin_amdgcn_cvt_pk_fp8_f32(v.z, v.w, r, true);
                fs8[i] = r;
            } else {
                int j = i - nS;
                float2 v = ((const float2*)feat_l)[j];
                flb[j] = pack_bf16x2(v.x, v.y);
            }
        }
    } else if (b < B_LINK + B_CVT + B_PACK) {
        // ---- layer weights: fold projections, pack to B-fragment order ----
        // Logical Wc[l] (320x128) = [[Wsu+Wst];[W_fs@Wnu];[W_fl@Wnt]]
        int i = (b - B_LINK - B_CVT) * 256 + tid;   // exactly covers total
        int j = i & 7;
        int lane = (i >> 3) & 63;
        int nt = (i >> 9) & 7;
        int ktAll = i >> 12;                 // 0..29
        int l = ktAll / 10;
        int kt = ktAll - l * 10;
        int k = kt * 32 + (lane >> 4) * 8 + j;
        int n = nt * 16 + (lane & 15);
        const size_t WL = (size_t)l * H_ * H_;
        float v;
        if (k < 128) {
            v = Wsu[WL + k * H_ + n] + Wst[WL + k * H_ + n];
        } else if (k < 192) {
            int a = k - 128;
            v = 0.f;
            for (int t = 0; t < 128; t++) v += W_fs[a * H_ + t] * Wnu[WL + t * H_ + n];
        } else {
            int a = k - 192;
            v = 0.f;
            for (int t = 0; t < 128; t++) v += W_fl[a * H_ + t] * Wnt[WL + t * H_ + n];
        }
        WpL[i] = bf_rne(v);
    } else if (b < B_LINK + B_CVT + B_PACK + B_BC) {
        // ---- bc[l] = bu+bt + b_fs@Wnu[l] + b_fl@Wnt[l] ----
        int i = (b - B_LINK - B_CVT - B_PACK) * 256 + tid;
        if (i < 3 * H_) {
            int l = i >> 7, c = i & 127;
            const size_t WL = (size_t)l * H_ * H_;
            float v = bu[i] + bt[i];
            for (int j2 = 0; j2 < 128; j2++)
                v += b_fs[j2] * Wnu[WL + j2 * H_ + c] + b_fl[j2] * Wnt[WL + j2 * H_ + c];
            bc[i] = v;
        }
    } else {
        // ---- concept projection, W_fc packed per-block into LDS ----
        const int bp = b - (B_LINK + B_CVT + B_PACK + B_BC);
        for (int idx = tid; idx < 4096; idx += 256) {
            int j = idx & 7;
            int lane = (idx >> 3) & 63;
            int nt = idx >> 9;
            int k = (lane >> 4) * 8 + j;          // 0..31
            int n = nt * 16 + (lane & 15);
            lw[idx] = bf_rne(W_fc[k * H_ + n]);
        }
        __syncthreads();
        const int lane = tid & 63;
        const int wv = tid >> 6;
        const int row0 = bp * 64 + wv * 16;
        const int q = lane >> 4;
        const int rA = min(row0 + (lane & 15), NC_ - 1);
        f32x4 acc[8];
#pragma unroll
        for (int i = 0; i < 8; i++) acc[i] = (f32x4){0.f, 0.f, 0.f, 0.f};
        const float* xp = feat_c + (size_t)rA * 32 + q * 8;
        float4 xa = *(const float4*)xp;
        float4 xb = *(const float4*)(xp + 4);
        bs8 af;
        af[0] = bf_rne(xa.x); af[1] = bf_rne(xa.y); af[2] = bf_rne(xa.z); af[3] = bf_rne(xa.w);
        af[4] = bf_rne(xb.x); af[5] = bf_rne(xb.y); af[6] = bf_rne(xb.z); af[7] = bf_rne(xb.w);
#pragma unroll
        for (int nt = 0; nt < 8; nt++) {
            bs8 bfr = *(const bs8*)(lw + (nt * 64 + lane) * 8);
            acc[nt] = __builtin_amdgcn_mfma_f32_16x16x32_bf16(af, bfr, acc[nt], 0, 0, 0);
        }
        const int colb = lane & 15;
#pragma unroll
        for (int nt = 0; nt < 8; nt++) {
            int col = nt * 16 + colb;
            float bv = b_fc[col];
#pragma unroll
            for (int r = 0; r < 4; r++) {
                int row = row0 + q * 4 + r;
                if (row < NC_) hc2A[(size_t)row * H_ + col] = bf_rne(acc[nt][r] + bv);
            }
        }
    }
}

// ---------------------------------------------------------------------------
// K2: fused aggregation.
// und: 8 lanes/dst, uint2 (8 fp8 feats)/lane, 8 chains/dst.
// tea: 32 lanes/dst, uint2 (4 bf16 feats)/lane, 4 chains/dst.
#define UB_ (NC_ / 32)   // 625 blocks, 32 dsts each
#define TB_ (NC_ / 8)    // 2500 blocks, 8 dsts each

__global__ __launch_bounds__(256) void agg_fused_kernel(
    const uint2* __restrict__ fs8, const int* __restrict__ headU,
    const int2* __restrict__ nxt2U, unsigned* __restrict__ aggFu,
    const uint2* __restrict__ flb2, const int* __restrict__ headT,
    const int2* __restrict__ nxt2T, unsigned* __restrict__ aggFt)
{
    const int b = blockIdx.x;
    const int tid = threadIdx.x;
    if (b < UB_) {
        const int c = b * 32 + (tid >> 3);
        const int sub = tid & 7;                 // uint2 index in 8-uint2 row
        int2 e[8];
#pragma unroll
        for (int j = 0; j < 8; j++) {
            int p = headU[c * 8 + j];
            e[j] = (p >= 0) ? nxt2U[p] : make_int2(-1, -1);
        }
        float a[8];
#pragma unroll
        for (int i = 0; i < 8; i++) a[i] = 0.f;
        int cnt = 0;
        for (;;) {
            int m = e[0].x;
#pragma unroll
            for (int j = 1; j < 8; j++) m &= e[j].x;
            if (m < 0) break;
            int2 f[8];
#pragma unroll
            for (int j = 0; j < 8; j++)
                f[j] = (e[j].y >= 0) ? nxt2U[e[j].y] : make_int2(-1, -1);
#pragma unroll
            for (int j = 0; j < 8; j++) {
                if (e[j].x >= 0) {
                    uint2 w = fs8[(size_t)e[j].x * 8 + sub];
                    v2f p0 = __builtin_amdgcn_cvt_pk_f32_fp8(w.x, false);
                    v2f p1 = __builtin_amdgcn_cvt_pk_f32_fp8(w.x, true);
                    v2f p2 = __builtin_amdgcn_cvt_pk_f32_fp8(w.y, false);
                    v2f p3 = __builtin_amdgcn_cvt_pk_f32_fp8(w.y, true);
                    a[0] += p0.x; a[1] += p0.y; a[2] += p1.x; a[3] += p1.y;
                    a[4] += p2.x; a[5] += p2.y; a[6] += p3.x; a[7] += p3.y;
                    cnt++;
                }
            }
#pragma unroll
            for (int j = 0; j < 8; j++) e[j] = f[j];
        }
        float inv = 1.f / (float)(cnt > 0 ? cnt : 1);
        uint4 o;
        o.x = pack_bf16x2(a[0] * inv, a[1] * inv);
        o.y = pack_bf16x2(a[2] * inv, a[3] * inv);
        o.z = pack_bf16x2(a[4] * inv, a[5] * inv);
        o.w = pack_bf16x2(a[6] * inv, a[7] * inv);
        ((uint4*)aggFu)[(size_t)c * 8 + sub] = o;   // row = 32 uints = 8 uint4
    } else {
        const int c = (b - UB_) * 8 + (tid >> 5);
        const int sub = tid & 31;                // uint2 index in 32-uint2 row
        int2 e[4];
#pragma unroll
        for (int j = 0; j < 4; j++) {
            int p = headT[c * 4 + j];
            e[j] = (p >= 0) ? nxt2T[p] : make_int2(-1, -1);
        }
        float a0 = 0.f, a1 = 0.f, a2 = 0.f, a3 = 0.f;
        int cnt = 0;
        for (;;) {
            int m = e[0].x & e[1].x & e[2].x & e[3].x;
            if (m < 0) break;
            int2 f[4];
#pragma unroll
            for (int j = 0; j < 4; j++)
                f[j] = (e[j].y >= 0) ? nxt2T[e[j].y] : make_int2(-1, -1);
#pragma unroll
            for (int j = 0; j < 4; j++) {
                if (e[j].x >= 0) {
                    uint2 w = flb2[(size_t)e[j].x * 32 + sub];
                    a0 += bflo(w.x); a1 += bfhi(w.x);
                    a2 += bflo(w.y); a3 += bfhi(w.y);
                    cnt++;
                }
            }
#pragma unroll
            for (int j = 0; j < 4; j++) e[j] = f[j];
        }
        float inv = 1.f / (float)(cnt > 0 ? cnt : 1);
        uint2 o;
        o.x = pack_bf16x2(a0 * inv, a1 * inv);
        o.y = pack_bf16x2(a2 * inv, a3 * inv);
        ((uint2*)aggFt)[(size_t)c * 32 + sub] = o;  // row = 64 uints = 32 uint2
    }
}

// ---------------------------------------------------------------------------
// One SAGE layer via MFMA, K=320: [hc(128) | aggFu(64) | aggFt(128)]
// out = act(scale*(A @ Wc' + bc)); FINAL writes fp32, no relu.
template <bool FINAL>
__global__ __launch_bounds__(256) void layer_mfma(
    const unsigned* __restrict__ A0, const unsigned* __restrict__ A1,
    const unsigned* __restrict__ A2, const short* __restrict__ Wp,
    const float* __restrict__ bias, float scale,
    short* __restrict__ out_bf, float* __restrict__ out_f32, int n)
{
    const int lane = threadIdx.x & 63;
    const int wv = threadIdx.x >> 6;
    const int row0 = blockIdx.x * 64 + wv * 16;
    const int q = lane >> 4;
    const int rA = min(row0 + (lane & 15), n - 1);
    f32x4 acc[8];
#pragma unroll
    for (int i = 0; i < 8; i++) acc[i] = (f32x4){0.f, 0.f, 0.f, 0.f};
#pragma unroll
    for (int kt = 0; kt < 10; kt++) {
        const unsigned* A;
        int rowU, off;
        if (kt < 4)      { A = A0; rowU = 64; off = kt * 16; }
        else if (kt < 6) { A = A1; rowU = 32; off = (kt - 4) * 16; }
        else             { A = A2; rowU = 64; off = (kt - 6) * 16; }
        bs8 af = *(const bs8*)(A + (size_t)rA * rowU + off + q * 4);
        const short* wp = Wp + (size_t)kt * 8 * 512;
#pragma unroll
        for (int nt = 0; nt < 8; nt++) {
            bs8 bfr = *(const bs8*)(wp + ((size_t)nt * 64 + lane) * 8);
            acc[nt] = __builtin_amdgcn_mfma_f32_16x16x32_bf16(af, bfr, acc[nt], 0, 0, 0);
        }
    }
    const int colb = lane & 15;
#pragma unroll
    for (int nt = 0; nt < 8; nt++) {
        int col = nt * 16 + colb;
        float bv = bias[col];
#pragma unroll
        for (int r = 0; r < 4; r++) {
            int row = row0 + q * 4 + r;
            if (row < n) {
                float v = (acc[nt][r] + bv) * scale;
                if constexpr (!FINAL) {
                    v = fmaxf(v, 0.f);
                    out_bf[(size_t)row * H_ + col] = bf_rne(v);
                } else {
                    out_f32[(size_t)row * H_ + col] = v;
                }
            }
        }
    }
}

// ---------------------------------------------------------------------------
extern "C" void kernel_launch(void* const* d_in, const int* in_sizes, int n_in,
                              void* d_out, int out_size, void* d_ws, size_t ws_size,
                              hipStream_t stream)
{
    (void)in_sizes; (void)n_in; (void)out_size; (void)ws_size;
    const float* feat_s = (const float*)d_in[0];
    const float* feat_c = (const float*)d_in[1];
    const float* feat_l = (const float*)d_in[2];
    const float* W_fs = (const float*)d_in[3];
    const float* b_fs = (const float*)d_in[4];
    const float* W_fc = (const float*)d_in[5];
    const float* b_fc = (const float*)d_in[6];
    const float* W_fl = (const float*)d_in[7];
    const float* b_fl = (const float*)d_in[8];
    const float* W_self_u  = (const float*)d_in[9];
    const float* W_neigh_u = (const float*)d_in[10];
    const float* b_u = (const float*)d_in[11];
    const float* W_self_t  = (const float*)d_in[12];
    const float* W_neigh_t = (const float*)d_in[13];
    const float* b_t = (const float*)d_in[14];
    const int* und_src = (const int*)d_in[15];
    const int* und_dst = (const int*)d_in[16];
    const int* tea_src = (const int*)d_in[17];
    const int* tea_dst = (const int*)d_in[18];
    float* out = (float*)d_out;

    // workspace layout (256B-aligned slices), ~42 MB total
    char* ws = (char*)d_ws;
    size_t o = 0;
    auto alloc = [&](size_t bytes) -> char* {
        char* p = ws + o;
        o += (bytes + 255) & ~(size_t)255;
        return p;
    };
    unsigned* fs8  = (unsigned*)alloc((size_t)NS_ * 16 * 4);   // feat_s fp8 [NS][64]
    unsigned* flb  = (unsigned*)alloc((size_t)NL_ * 64 * 4);   // feat_l bf16 [NL][128]
    short* hc2A = (short*)alloc((size_t)NC_ * H_ * 2);
    short* hc2B = (short*)alloc((size_t)NC_ * H_ * 2);
    unsigned* aggFu = (unsigned*)alloc((size_t)NC_ * 32 * 4);  // mean feat_s bf16 [NC][64]
    unsigned* aggFt = (unsigned*)alloc((size_t)NC_ * 64 * 4);  // mean feat_l bf16 [NC][128]
    short* WpL = (short*)alloc((size_t)3 * 10 * 8 * 64 * 8 * 2);
    float* bc  = (float*)alloc((size_t)3 * H_ * 4);
    int* headU = (int*)alloc((size_t)8 * NC_ * 4);   // 640000 B (mult of 256)
    int* headT = (int*)alloc((size_t)4 * NC_ * 4);   // contiguous with headU
    int2* nxt2U = (int2*)alloc((size_t)EU_ * 8);
    int2* nxt2T = (int2*)alloc((size_t)ET_ * 8);

    // heads = -1 (U + T contiguous)
    hipMemsetAsync(headU, 0xFF, (size_t)12 * NC_ * 4, stream);

    // K1: all prep fused (link || cvt || weight-fold/pack || bc || concept proj)
    prep_fused_kernel<<<B_TOTAL, 256, 0, stream>>>(
        und_dst, und_src, tea_dst, tea_src, headU, headT, nxt2U, nxt2T,
        feat_s, fs8, feat_l, flb,
        W_self_u, W_neigh_u, W_self_t, W_neigh_t, W_fs, W_fl, WpL,
        b_u, b_t, b_fs, b_fl, bc,
        feat_c, W_fc, b_fc, hc2A);

    // K2: neighbor feature means (und fp8 + tea bf16)
    agg_fused_kernel<<<UB_ + TB_, 256, 0, stream>>>(
        (const uint2*)fs8, headU, nxt2U, aggFu,
        (const uint2*)flb, headT, nxt2T, aggFt);

    // K3-K5: hetero SAGE layers (scale 0.5 on layer 0; relu on 0,1; final fp32)
    layer_mfma<false><<<(NC_ + 63) / 64, 256, 0, stream>>>(
        (const unsigned*)hc2A, aggFu, aggFt, WpL, bc, 0.5f, hc2B, nullptr, NC_);
    layer_mfma<false><<<(NC_ + 63) / 64, 256, 0, stream>>>(
        (const unsigned*)hc2B, aggFu, aggFt, WpL + 40960, bc + H_, 1.0f, hc2A, nullptr, NC_);
    layer_mfma<true><<<(NC_ + 63) / 64, 256, 0, stream>>>(
        (const unsigned*)hc2A, aggFu, aggFt, WpL + 2 * 40960, bc + 2 * H_, 1.0f,
        nullptr, out, NC_);
}